// Round 8
// baseline (208.054 us; speedup 1.0000x reference)
//
#include <hip/hip_runtime.h>

typedef _Float16 half8 __attribute__((ext_vector_type(8)));
typedef _Float16 half4v __attribute__((ext_vector_type(4)));
typedef _Float16 half2v __attribute__((ext_vector_type(2)));
typedef float f32x4 __attribute__((ext_vector_type(4)));
typedef float f32x16 __attribute__((ext_vector_type(16)));

__device__ __forceinline__ half8 cvt8(const float4 a, const float4 b) {
    half8 r;
    r[0] = (_Float16)a.x; r[1] = (_Float16)a.y; r[2] = (_Float16)a.z; r[3] = (_Float16)a.w;
    r[4] = (_Float16)b.x; r[5] = (_Float16)b.y; r[6] = (_Float16)b.z; r[7] = (_Float16)b.w;
    return r;
}

// ---------------------------------------------------------------- QKV projections
// One launch, z in {0:Q, 1:K, 2:V-scatter}. A,B are f32 with inline cvt during
// staging (kills the cvt pass). Core = proven 64x64 gemm_tn.
__global__ __launch_bounds__(256) void qkv_kernel(
    const float* __restrict__ det, const float* __restrict__ trk,
    const float* __restrict__ wq, const float* __restrict__ wk,
    const float* __restrict__ wv, const float* __restrict__ bq,
    const float* __restrict__ bk, const float* __restrict__ bv,
    _Float16* __restrict__ Qh, _Float16* __restrict__ Kh,
    _Float16* __restrict__ vt)
{
    int z = blockIdx.z;
    const float* A    = (z == 0) ? det : trk;
    const float* Bm   = (z == 0) ? wq : (z == 1) ? wk : wv;
    const float* bias = (z == 0) ? bq : (z == 1) ? bk : bv;

    __shared__ _Float16 As[64][40];
    __shared__ _Float16 Bs[64][40];

    int tid = threadIdx.x, l = tid & 63, w = tid >> 6;
    int wm = (w >> 1) * 32, wn = (w & 1) * 32;
    int m0 = blockIdx.x * 64, n0 = blockIdx.y * 64;
    int lr = tid >> 2, lc = (tid & 3) * 8;
    int ko = (l >> 4) * 8, l15 = l & 15;

    f32x4 acc[2][2]{};

    for (int k0 = 0; k0 < 256; k0 += 32) {
        float4 a0 = *(const float4*)(A + (long)(m0 + lr) * 256 + k0 + lc);
        float4 a1 = *(const float4*)(A + (long)(m0 + lr) * 256 + k0 + lc + 4);
        float4 b0 = *(const float4*)(Bm + (long)(n0 + lr) * 256 + k0 + lc);
        float4 b1 = *(const float4*)(Bm + (long)(n0 + lr) * 256 + k0 + lc + 4);
        __syncthreads();
        *(half8*)&As[lr][lc] = cvt8(a0, a1);
        *(half8*)&Bs[lr][lc] = cvt8(b0, b1);
        __syncthreads();
        half8 af0 = *(const half8*)(&As[wm + l15][ko]);
        half8 af1 = *(const half8*)(&As[wm + 16 + l15][ko]);
        half8 bf0 = *(const half8*)(&Bs[wn + l15][ko]);
        half8 bf1 = *(const half8*)(&Bs[wn + 16 + l15][ko]);
        acc[0][0] = __builtin_amdgcn_mfma_f32_16x16x32_f16(af0, bf0, acc[0][0], 0, 0, 0);
        acc[0][1] = __builtin_amdgcn_mfma_f32_16x16x32_f16(af0, bf1, acc[0][1], 0, 0, 0);
        acc[1][0] = __builtin_amdgcn_mfma_f32_16x16x32_f16(af1, bf0, acc[1][0], 0, 0, 0);
        acc[1][1] = __builtin_amdgcn_mfma_f32_16x16x32_f16(af1, bf1, acc[1][1], 0, 0, 0);
    }

    // C layout: col = lane&15 (B-row), row = (lane>>4)*4 + i (A-row) [proven]
    #pragma unroll
    for (int mm = 0; mm < 2; ++mm)
    #pragma unroll
    for (int nn = 0; nn < 2; ++nn) {
        int row  = wm + mm * 16 + (l >> 4) * 4;
        int colg = n0 + wn + nn * 16 + l15;
        float bc = bias[colg];
        if (z == 2) {
            half4v hv;
            #pragma unroll
            for (int i = 0; i < 4; ++i) hv[i] = (_Float16)(acc[mm][nn][i] + bc);
            int grow = m0 + row;             // = b*512 + t (4 consecutive t)
            int bb = grow >> 9, t = grow & 511;
            long off = ((long)(bb * 8 + (colg >> 5)) * 32 + (colg & 31)) * 512 + t;
            *(half4v*)(vt + off) = hv;
        } else {
            _Float16* C = (z == 0) ? Qh : Kh;
            #pragma unroll
            for (int i = 0; i < 4; ++i)
                C[(long)(m0 + row + i) * 256 + colg] = (_Float16)(acc[mm][nn][i] + bc);
        }
    }
}

// ---------------------------------------------------------------- fused attention
// Unchanged from round 6 (passed). One block = 64 q x (b,h); online softmax,
// 2 k-phases, s[16] live; denominator xor16/xor32-reduced before normalize.
__global__ __launch_bounds__(256) void flash_kernel(
    const _Float16* __restrict__ Q, const _Float16* __restrict__ K,
    const _Float16* __restrict__ vt, _Float16* __restrict__ ctx)
{
    __shared__ _Float16 P[4][16][264];
    int bh = blockIdx.y, b = bh >> 3, h = bh & 7;
    int q0 = blockIdx.x * 64;
    int tid = threadIdx.x, l = tid & 63, w = tid >> 6;
    int l15 = l & 15, g = l >> 4;

    const _Float16* qp = Q + ((long)b * 512 + q0 + w * 16 + l15) * 256 + h * 32 + g * 8;
    half8 qf = *(const half8*)qp;
    #pragma unroll
    for (int i = 0; i < 8; ++i) qf[i] = qf[i] * (_Float16)0.17677669529663687f;

    const _Float16* kp = K + ((long)b * 512 + l15) * 256 + h * 32 + g * 8;
    const _Float16* vp = vt + ((long)bh * 32 + l15) * 512 + g * 8;

    f32x4 c0{}, c1{};
    float m_run = -3e38f, sum_run = 0.f;
    f32x4 zero{};

    #pragma unroll
    for (int hf = 0; hf < 2; ++hf) {
        f32x4 s[16];
        #pragma unroll
        for (int t = 0; t < 16; ++t) {
            half8 kf = *(const half8*)(kp + (long)(hf * 16 + t) * (16 * 256));
            s[t] = __builtin_amdgcn_mfma_f32_16x16x32_f16(kf, qf, zero, 0, 0, 0);
        }
        float m0 = -3e38f, m1 = -3e38f, m2 = -3e38f, m3 = -3e38f;
        #pragma unroll
        for (int t = 0; t < 16; ++t) {
            m0 = fmaxf(m0, s[t][0]); m1 = fmaxf(m1, s[t][1]);
            m2 = fmaxf(m2, s[t][2]); m3 = fmaxf(m3, s[t][3]);
        }
        float ml = fmaxf(fmaxf(m0, m1), fmaxf(m2, m3));
        ml = fmaxf(ml, __shfl_xor(ml, 16, 64));
        ml = fmaxf(ml, __shfl_xor(ml, 32, 64));
        float m_new = fmaxf(m_run, ml);
        float scale = __expf(m_run - m_new);
        #pragma unroll
        for (int i = 0; i < 4; ++i) { c0[i] *= scale; c1[i] *= scale; }
        sum_run *= scale;
        float s0 = 0.f, s1 = 0.f, s2 = 0.f, s3 = 0.f;
        #pragma unroll
        for (int t = 0; t < 16; ++t) {
            s[t][0] = __expf(s[t][0] - m_new); s0 += s[t][0];
            s[t][1] = __expf(s[t][1] - m_new); s1 += s[t][1];
            s[t][2] = __expf(s[t][2] - m_new); s2 += s[t][2];
            s[t][3] = __expf(s[t][3] - m_new); s3 += s[t][3];
        }
        sum_run += (s0 + s1) + (s2 + s3);
        m_run = m_new;

        #pragma unroll
        for (int t = 0; t < 16; ++t) {
            half2v p01, p23;
            p01[0] = (_Float16)s[t][0]; p01[1] = (_Float16)s[t][1];
            p23[0] = (_Float16)s[t][2]; p23[1] = (_Float16)s[t][3];
            *(half2v*)&P[w][l15][t * 16 + g * 4]     = p01;
            *(half2v*)&P[w][l15][t * 16 + g * 4 + 2] = p23;
        }
        #pragma unroll
        for (int s2i = 0; s2i < 8; ++s2i) {
            half8 bf = *(const half8*)&P[w][l15][s2i * 32 + g * 8];
            half8 a0 = *(const half8*)(vp + hf * 256 + s2i * 32);
            half8 a1 = *(const half8*)(vp + 16 * 512 + hf * 256 + s2i * 32);
            c0 = __builtin_amdgcn_mfma_f32_16x16x32_f16(a0, bf, c0, 0, 0, 0);
            c1 = __builtin_amdgcn_mfma_f32_16x16x32_f16(a1, bf, c1, 0, 0, 0);
        }
    }
    sum_run += __shfl_xor(sum_run, 16, 64);
    sum_run += __shfl_xor(sum_run, 32, 64);
    float rs = 1.f / sum_run;
    _Float16* cp = ctx + ((long)b * 512 + q0 + w * 16 + l15) * 256 + h * 32;
    #pragma unroll
    for (int i = 0; i < 4; ++i) {
        cp[g * 4 + i]      = (_Float16)(c0[i] * rs);
        cp[16 + g * 4 + i] = (_Float16)(c1[i] * rs);
    }
}

// ---------------------------------------------------------------- out-proj + LN
// Block = 64 rows x all 256 cols (wave w -> cols [64w,64w+64), acc 4x4).
// Epilogue: x = acc + bo + det; per-row sum/sumsq via 16-lane butterfly +
// cross-wave LDS reduce; xn = (x-mu)*rsqrt(var+eps)*g + beta -> f16.
__global__ __launch_bounds__(256) void outln_kernel(
    const _Float16* __restrict__ ctx, const float* __restrict__ wo,
    const float* __restrict__ bo, const float* __restrict__ det,
    const float* __restrict__ lng, const float* __restrict__ lnb,
    _Float16* __restrict__ xn)
{
    __shared__ _Float16 As[64][40];
    __shared__ _Float16 Bs[256][40];
    __shared__ float redS[4][64], redQ[4][64], mu[64], rsv[64];

    int tid = threadIdx.x, l = tid & 63, w = tid >> 6;
    int m0 = blockIdx.x * 64;
    int wn = w * 64;
    int lr = tid >> 2, lc = (tid & 3) * 8;
    int ko = (l >> 4) * 8, l15 = l & 15, g4 = l >> 4;

    f32x4 acc[4][4]{};

    for (int k0 = 0; k0 < 256; k0 += 32) {
        half8 av = *(const half8*)(ctx + (long)(m0 + lr) * 256 + k0 + lc);
        float4 f[8];
        #pragma unroll
        for (int i = 0; i < 8; ++i)
            f[i] = *(const float4*)(wo + (long)tid * 256 + k0 + i * 4);
        __syncthreads();
        *(half8*)&As[lr][lc] = av;
        #pragma unroll
        for (int i = 0; i < 4; ++i)
            *(half8*)&Bs[tid][i * 8] = cvt8(f[2 * i], f[2 * i + 1]);
        __syncthreads();
        half8 afr[4], bfr[4];
        #pragma unroll
        for (int mm = 0; mm < 4; ++mm) afr[mm] = *(const half8*)&As[mm * 16 + l15][ko];
        #pragma unroll
        for (int nn = 0; nn < 4; ++nn) bfr[nn] = *(const half8*)&Bs[wn + nn * 16 + l15][ko];
        #pragma unroll
        for (int mm = 0; mm < 4; ++mm)
            #pragma unroll
            for (int nn = 0; nn < 4; ++nn)
                acc[mm][nn] = __builtin_amdgcn_mfma_f32_16x16x32_f16(afr[mm], bfr[nn], acc[mm][nn], 0, 0, 0);
    }

    float bov[4], gv[4], bev[4];
    #pragma unroll
    for (int nn = 0; nn < 4; ++nn) {
        int c = wn + nn * 16 + l15;
        bov[nn] = bo[c]; gv[nn] = lng[c]; bev[nn] = lnb[c];
    }
    // x = acc + bo + det; accumulate row sums over this wave's 64 cols
    #pragma unroll
    for (int mm = 0; mm < 4; ++mm)
    #pragma unroll
    for (int i = 0; i < 4; ++i) {
        int r = mm * 16 + g4 * 4 + i;
        float s = 0.f, q = 0.f;
        #pragma unroll
        for (int nn = 0; nn < 4; ++nn) {
            float x = acc[mm][nn][i] + bov[nn]
                    + det[(long)(m0 + r) * 256 + wn + nn * 16 + l15];
            acc[mm][nn][i] = x;
            s += x; q += x * x;
        }
        #pragma unroll
        for (int off = 1; off < 16; off <<= 1) {
            s += __shfl_xor(s, off, 64);
            q += __shfl_xor(q, off, 64);
        }
        if (l15 == 0) { redS[w][r] = s; redQ[w][r] = q; }
    }
    __syncthreads();
    if (tid < 64) {
        float S = redS[0][tid] + redS[1][tid] + redS[2][tid] + redS[3][tid];
        float Qs = redQ[0][tid] + redQ[1][tid] + redQ[2][tid] + redQ[3][tid];
        float mean = S * (1.f / 256.f);
        float var = Qs * (1.f / 256.f) - mean * mean;
        mu[tid] = mean;
        rsv[tid] = rsqrtf(var + 1e-5f);
    }
    __syncthreads();
    #pragma unroll
    for (int mm = 0; mm < 4; ++mm)
    #pragma unroll
    for (int i = 0; i < 4; ++i) {
        int r = mm * 16 + g4 * 4 + i;
        float mr = mu[r], rr = rsv[r];
        #pragma unroll
        for (int nn = 0; nn < 4; ++nn)
            xn[(long)(m0 + r) * 256 + wn + nn * 16 + l15] =
                (_Float16)((acc[mm][nn][i] - mr) * rr * gv[nn] + bev[nn]);
    }
}

// ---------------------------------------------------------------- pairwise MLP
// 32x32x16 MFMA version: per wave, h' [32w,+32) on reg axis, n [n0,+32) on
// lane axis, 16 MFMA/tl (was 32). C layout: col=lane&31, row=(reg&3)+8*(reg>>2)
// +4*(lane>>5) [m74/m101]. Epilogue: 16 in-reg relu*fma + one shfl_xor(32).
__global__ __launch_bounds__(256) void mlp_kernel(
    const _Float16* __restrict__ xn, const float* __restrict__ trk,
    const float* __restrict__ w1, const float* __restrict__ w2,
    const float* __restrict__ b1, const float* __restrict__ b2,
    float* __restrict__ out)
{
    int b = blockIdx.z, n0g = blockIdx.x * 32, t0 = blockIdx.y * 32;
    int tid = threadIdx.x, l = tid & 63, w = tid >> 6;
    int l31 = l & 31, hk = (l >> 5) * 8;   // k-slice base within K=16

    __shared__ _Float16 ts[32][264];
    __shared__ float part[4][32][33];

    // stage trk f32 -> f16 tile 32x256
    {
        const float* src = trk + ((long)b * 512 + t0) * 256;
        int r = tid >> 3, c0s = (tid & 7) * 32;
        float4 f[8];
        #pragma unroll
        for (int i = 0; i < 8; ++i)
            f[i] = *(const float4*)(src + (long)r * 256 + c0s + i * 4);
        #pragma unroll
        for (int i = 0; i < 4; ++i)
            *(half8*)&ts[r][c0s + i * 8] = cvt8(f[2 * i], f[2 * i + 1]);
    }

    // A frags: w1 row h' = w*32 + l31, k = ks*16 + hk + j  (f32 inline cvt)
    half8 wf[16];
    {
        const float* wp = w1 + (long)(w * 32 + l31) * 256 + hk;
        #pragma unroll
        for (int ks = 0; ks < 16; ++ks) {
            float4 fa = *(const float4*)(wp + ks * 16);
            float4 fb = *(const float4*)(wp + ks * 16 + 4);
            wf[ks] = cvt8(fa, fb);
        }
    }
    // B frags: xn row n = n0g + l31 (f16)
    half8 bx[16];
    {
        const _Float16* xb = xn + ((long)b * 512 + n0g + l31) * 256 + hk;
        #pragma unroll
        for (int ks = 0; ks < 16; ++ks)
            bx[ks] = *(const half8*)(xb + ks * 16);
    }
    // b1/w2 mapped to C reg axis: h'' = w*32 + (r&3) + 8*(r>>2) + 4*(l>>5)
    f32x16 binit, w2v;
    #pragma unroll
    for (int r = 0; r < 16; ++r) {
        int hh = w * 32 + (r & 3) + 8 * (r >> 2) + 4 * (l >> 5);
        binit[r] = b1[hh];
        w2v[r]  = w2[hh];
    }

    __syncthreads();

    for (int tl = 0; tl < 32; ++tl) {
        f32x16 acc = binit;
        #pragma unroll
        for (int ks = 0; ks < 16; ++ks) {
            half8 tf = *(const half8*)&ts[tl][ks * 16 + hk];  // bcast (2 addrs)
            half8 sa = wf[ks] * tf;                            // v_pk_mul_f16 x4
            acc = __builtin_amdgcn_mfma_f32_32x32x16_f16(sa, bx[ks], acc, 0, 0, 0);
        }
        float x = 0.f;
        #pragma unroll
        for (int r = 0; r < 16; ++r)
            x = fmaf(fmaxf(acc[r], 0.f), w2v[r], x);
        x += __shfl_xor(x, 32, 64);   // combine the two 16-row halves
        if (l < 32) part[w][tl][l] = x;
    }
    __syncthreads();

    // combine 4 wave partials + bias, sigmoid, store (proven round-6 pattern)
    float b2v = b2[0];
    int t = tid & 31, nbase = tid >> 5;
    float* op = out + ((long)b * 512 + n0g) * 512 + t0;
    #pragma unroll
    for (int k = 0; k < 4; ++k) {
        int nn = nbase + k * 8;
        float s = part[0][t][nn] + part[1][t][nn]
                + part[2][t][nn] + part[3][t][nn] + b2v;
        op[(long)nn * 512 + t] = 1.f / (1.f + __expf(-s));
    }
}

// ---------------------------------------------------------------- launch
extern "C" void kernel_launch(void* const* d_in, const int* in_sizes, int n_in,
                              void* d_out, int out_size, void* d_ws, size_t ws_size,
                              hipStream_t stream)
{
    const float* det  = (const float*)d_in[0];
    const float* trk  = (const float*)d_in[1];
    const float* w_q  = (const float*)d_in[2];
    const float* b_q  = (const float*)d_in[3];
    const float* w_k  = (const float*)d_in[4];
    const float* b_k  = (const float*)d_in[5];
    const float* w_v  = (const float*)d_in[6];
    const float* b_v  = (const float*)d_in[7];
    const float* w_o  = (const float*)d_in[8];
    const float* b_o  = (const float*)d_in[9];
    const float* ln_g = (const float*)d_in[10];
    const float* ln_b = (const float*)d_in[11];
    const float* w1   = (const float*)d_in[12];
    const float* b1   = (const float*)d_in[13];
    const float* w2   = (const float*)d_in[14];
    const float* b2   = (const float*)d_in[15];
    float* out = (float*)d_out;

    char* ws = (char*)d_ws;
    _Float16* Q_h   = (_Float16*)(ws);
    _Float16* K_h   = (_Float16*)(ws + (size_t)1048576);
    _Float16* vt    = (_Float16*)(ws + (size_t)2097152);
    _Float16* ctx_h = (_Float16*)(ws + (size_t)3145728);
    _Float16* xn_h  = (_Float16*)(ws + (size_t)4194304);

    // Q/K/V projections (one launch, f32 inputs, inline cvt)
    qkv_kernel<<<dim3(32, 4, 3), 256, 0, stream>>>(
        det, trk, w_q, w_k, w_v, b_q, b_k, b_v, Q_h, K_h, vt);
    // fused scores + softmax + PV
    flash_kernel<<<dim3(8, 32), 256, 0, stream>>>(Q_h, K_h, vt, ctx_h);
    // out-proj + residual + LayerNorm -> xn f16
    outln_kernel<<<32, 256, 0, stream>>>(ctx_h, w_o, b_o, det, ln_g, ln_b, xn_h);
    // association MLP + sigmoid
    mlp_kernel<<<dim3(16, 16, 4), 256, 0, stream>>>(xn_h, trk, w1, w2, b1, b2, out);

    (void)in_sizes; (void)n_in; (void)out_size; (void)ws_size;
}

// Round 9
// 189.055 us; speedup vs baseline: 1.1005x; 1.1005x over previous
//
#include <hip/hip_runtime.h>

typedef _Float16 half8 __attribute__((ext_vector_type(8)));
typedef _Float16 half4v __attribute__((ext_vector_type(4)));
typedef _Float16 half2v __attribute__((ext_vector_type(2)));
typedef float f32x4 __attribute__((ext_vector_type(4)));

__device__ __forceinline__ half8 cvt8(const float4 a, const float4 b) {
    half8 r;
    r[0] = (_Float16)a.x; r[1] = (_Float16)a.y; r[2] = (_Float16)a.z; r[3] = (_Float16)a.w;
    r[4] = (_Float16)b.x; r[5] = (_Float16)b.y; r[6] = (_Float16)b.z; r[7] = (_Float16)b.w;
    return r;
}

// ---------------------------------------------------------------- QKV + cvt
// z in {0:Q, 1:K, 2:V-scatter, 3: trk/w1 f32->f16 cvt for mlp}.
// GEMM core = proven 64x64 gemm_tn with register prefetch of next k-step.
__global__ __launch_bounds__(256) void qkv_kernel(
    const float* __restrict__ det, const float* __restrict__ trk,
    const float* __restrict__ wq, const float* __restrict__ wk,
    const float* __restrict__ wv, const float* __restrict__ bq,
    const float* __restrict__ bk, const float* __restrict__ bv,
    const float* __restrict__ w1,
    _Float16* __restrict__ Qh, _Float16* __restrict__ Kh,
    _Float16* __restrict__ vt, _Float16* __restrict__ trk_h,
    _Float16* __restrict__ w1_h)
{
    int z = blockIdx.z;
    if (z == 3) {   // elementwise cvt: trk (131072 float4) + w1 (8192 float4)
        int flat = blockIdx.y * 32 + blockIdx.x;          // 0..127
        int t0 = flat * 256 + threadIdx.x;                // stride 32768
        for (int i = t0; i < 131072; i += 32768) {
            float4 v = ((const float4*)trk)[i];
            half4v h; h[0]=(_Float16)v.x; h[1]=(_Float16)v.y; h[2]=(_Float16)v.z; h[3]=(_Float16)v.w;
            *(half4v*)(trk_h + (long)i * 4) = h;
        }
        if (t0 < 8192) {
            float4 v = ((const float4*)w1)[t0];
            half4v h; h[0]=(_Float16)v.x; h[1]=(_Float16)v.y; h[2]=(_Float16)v.z; h[3]=(_Float16)v.w;
            *(half4v*)(w1_h + (long)t0 * 4) = h;
        }
        return;
    }
    const float* A    = (z == 0) ? det : trk;
    const float* Bm   = (z == 0) ? wq : (z == 1) ? wk : wv;
    const float* bias = (z == 0) ? bq : (z == 1) ? bk : bv;

    __shared__ _Float16 As[64][40];
    __shared__ _Float16 Bs[64][40];

    int tid = threadIdx.x, l = tid & 63, w = tid >> 6;
    int wm = (w >> 1) * 32, wn = (w & 1) * 32;
    int m0 = blockIdx.x * 64, n0 = blockIdx.y * 64;
    int lr = tid >> 2, lc = (tid & 3) * 8;
    int ko = (l >> 4) * 8, l15 = l & 15;

    f32x4 acc[2][2]{};

    // prefetch k0 = 0
    float4 a0 = *(const float4*)(A + (long)(m0 + lr) * 256 + lc);
    float4 a1 = *(const float4*)(A + (long)(m0 + lr) * 256 + lc + 4);
    float4 b0 = *(const float4*)(Bm + (long)(n0 + lr) * 256 + lc);
    float4 b1 = *(const float4*)(Bm + (long)(n0 + lr) * 256 + lc + 4);

    for (int k0 = 0; k0 < 256; k0 += 32) {
        __syncthreads();
        *(half8*)&As[lr][lc] = cvt8(a0, a1);
        *(half8*)&Bs[lr][lc] = cvt8(b0, b1);
        __syncthreads();
        if (k0 + 32 < 256) {   // issue next-step loads; overlap MFMA + barrier
            a0 = *(const float4*)(A + (long)(m0 + lr) * 256 + k0 + 32 + lc);
            a1 = *(const float4*)(A + (long)(m0 + lr) * 256 + k0 + 32 + lc + 4);
            b0 = *(const float4*)(Bm + (long)(n0 + lr) * 256 + k0 + 32 + lc);
            b1 = *(const float4*)(Bm + (long)(n0 + lr) * 256 + k0 + 32 + lc + 4);
        }
        half8 af0 = *(const half8*)(&As[wm + l15][ko]);
        half8 af1 = *(const half8*)(&As[wm + 16 + l15][ko]);
        half8 bf0 = *(const half8*)(&Bs[wn + l15][ko]);
        half8 bf1 = *(const half8*)(&Bs[wn + 16 + l15][ko]);
        acc[0][0] = __builtin_amdgcn_mfma_f32_16x16x32_f16(af0, bf0, acc[0][0], 0, 0, 0);
        acc[0][1] = __builtin_amdgcn_mfma_f32_16x16x32_f16(af0, bf1, acc[0][1], 0, 0, 0);
        acc[1][0] = __builtin_amdgcn_mfma_f32_16x16x32_f16(af1, bf0, acc[1][0], 0, 0, 0);
        acc[1][1] = __builtin_amdgcn_mfma_f32_16x16x32_f16(af1, bf1, acc[1][1], 0, 0, 0);
    }

    #pragma unroll
    for (int mm = 0; mm < 2; ++mm)
    #pragma unroll
    for (int nn = 0; nn < 2; ++nn) {
        int row  = wm + mm * 16 + (l >> 4) * 4;
        int colg = n0 + wn + nn * 16 + l15;
        float bc = bias[colg];
        if (z == 2) {
            half4v hv;
            #pragma unroll
            for (int i = 0; i < 4; ++i) hv[i] = (_Float16)(acc[mm][nn][i] + bc);
            int grow = m0 + row;
            int bb = grow >> 9, t = grow & 511;
            long off = ((long)(bb * 8 + (colg >> 5)) * 32 + (colg & 31)) * 512 + t;
            *(half4v*)(vt + off) = hv;
        } else {
            _Float16* C = (z == 0) ? Qh : Kh;
            #pragma unroll
            for (int i = 0; i < 4; ++i)
                C[(long)(m0 + row + i) * 256 + colg] = (_Float16)(acc[mm][nn][i] + bc);
        }
    }
}

// ---------------------------------------------------------------- fused attention
// 4-way k-split: block = 16 q x (b,h); wave w owns k-quarter [128w, 128w+128).
// Per wave: S^T = MFMA(K,Q) (k on reg axis, q = lane&15), local online softmax
// (m, sum xor16/32-reduced), PV over its quarter (unnormalized). Exact merge
// across waves via LDS: m* = max_w m_w; c = sum_w c_w e^{m_w-m*}; wave 0 stores.
__global__ __launch_bounds__(256) void flash_kernel(
    const _Float16* __restrict__ Q, const _Float16* __restrict__ K,
    const _Float16* __restrict__ vt, _Float16* __restrict__ ctx)
{
    __shared__ _Float16 P[4][16][136];    // per-wave P: [q16][k128 + 8 pad]
    __shared__ float cbuf[4][16][33];     // per-wave unnorm ctx [q][d32], pad
    __shared__ float mbuf[4][16], sbuf[4][16];

    int bh = blockIdx.y, b = bh >> 3, h = bh & 7;
    int q0 = blockIdx.x * 16;
    int tid = threadIdx.x, l = tid & 63, w = tid >> 6;
    int l15 = l & 15, g = l >> 4;

    const _Float16* qp = Q + ((long)b * 512 + q0 + l15) * 256 + h * 32 + g * 8;
    half8 qf = *(const half8*)qp;
    #pragma unroll
    for (int i = 0; i < 8; ++i) qf[i] = qf[i] * (_Float16)0.17677669529663687f;

    const _Float16* kp = K + ((long)b * 512 + w * 128 + l15) * 256 + h * 32 + g * 8;
    const _Float16* vp = vt + ((long)bh * 32 + l15) * 512 + w * 128 + g * 8;

    f32x4 zero{};
    f32x4 s[8];
    #pragma unroll
    for (int t = 0; t < 8; ++t) {
        half8 kf = *(const half8*)(kp + (long)t * (16 * 256));
        s[t] = __builtin_amdgcn_mfma_f32_16x16x32_f16(kf, qf, zero, 0, 0, 0);
    }
    // local max (per q = l15) over this k-quarter
    float m0 = -3e38f, m1 = -3e38f, m2 = -3e38f, m3 = -3e38f;
    #pragma unroll
    for (int t = 0; t < 8; ++t) {
        m0 = fmaxf(m0, s[t][0]); m1 = fmaxf(m1, s[t][1]);
        m2 = fmaxf(m2, s[t][2]); m3 = fmaxf(m3, s[t][3]);
    }
    float m_loc = fmaxf(fmaxf(m0, m1), fmaxf(m2, m3));
    m_loc = fmaxf(m_loc, __shfl_xor(m_loc, 16, 64));
    m_loc = fmaxf(m_loc, __shfl_xor(m_loc, 32, 64));
    float s0 = 0.f, s1 = 0.f, s2 = 0.f, s3 = 0.f;
    #pragma unroll
    for (int t = 0; t < 8; ++t) {
        s[t][0] = __expf(s[t][0] - m_loc); s0 += s[t][0];
        s[t][1] = __expf(s[t][1] - m_loc); s1 += s[t][1];
        s[t][2] = __expf(s[t][2] - m_loc); s2 += s[t][2];
        s[t][3] = __expf(s[t][3] - m_loc); s3 += s[t][3];
    }
    float sum_loc = (s0 + s1) + (s2 + s3);
    sum_loc += __shfl_xor(sum_loc, 16, 64);
    sum_loc += __shfl_xor(sum_loc, 32, 64);

    // stage unnormalized P and PV-accumulate over this quarter
    #pragma unroll
    for (int t = 0; t < 8; ++t) {
        half2v p01, p23;
        p01[0] = (_Float16)s[t][0]; p01[1] = (_Float16)s[t][1];
        p23[0] = (_Float16)s[t][2]; p23[1] = (_Float16)s[t][3];
        *(half2v*)&P[w][l15][t * 16 + g * 4]     = p01;
        *(half2v*)&P[w][l15][t * 16 + g * 4 + 2] = p23;
    }
    f32x4 c0{}, c1{};
    #pragma unroll
    for (int s2i = 0; s2i < 4; ++s2i) {
        half8 bf = *(const half8*)&P[w][l15][s2i * 32 + g * 8];
        half8 a0 = *(const half8*)(vp + s2i * 32);
        half8 a1 = *(const half8*)(vp + 16 * 512 + s2i * 32);
        c0 = __builtin_amdgcn_mfma_f32_16x16x32_f16(a0, bf, c0, 0, 0, 0);
        c1 = __builtin_amdgcn_mfma_f32_16x16x32_f16(a1, bf, c1, 0, 0, 0);
    }
    // publish (m, sum, c) for merge
    if (g == 0) { mbuf[w][l15] = m_loc; sbuf[w][l15] = sum_loc; }
    #pragma unroll
    for (int i = 0; i < 4; ++i) {
        cbuf[w][l15][g * 4 + i]      = c0[i];
        cbuf[w][l15][16 + g * 4 + i] = c1[i];
    }
    __syncthreads();
    if (w == 0) {
        float ma = fmaxf(fmaxf(mbuf[0][l15], mbuf[1][l15]),
                         fmaxf(mbuf[2][l15], mbuf[3][l15]));
        float e0 = __expf(mbuf[0][l15] - ma), e1 = __expf(mbuf[1][l15] - ma);
        float e2 = __expf(mbuf[2][l15] - ma), e3 = __expf(mbuf[3][l15] - ma);
        float den = sbuf[0][l15] * e0 + sbuf[1][l15] * e1
                  + sbuf[2][l15] * e2 + sbuf[3][l15] * e3;
        float rs = 1.f / den;
        _Float16* cp = ctx + ((long)b * 512 + q0 + l15) * 256 + h * 32;
        #pragma unroll
        for (int i = 0; i < 4; ++i) {
            int d0 = g * 4 + i, d1 = 16 + g * 4 + i;
            float v0 = cbuf[0][l15][d0] * e0 + cbuf[1][l15][d0] * e1
                     + cbuf[2][l15][d0] * e2 + cbuf[3][l15][d0] * e3;
            float v1 = cbuf[0][l15][d1] * e0 + cbuf[1][l15][d1] * e1
                     + cbuf[2][l15][d1] * e2 + cbuf[3][l15][d1] * e3;
            cp[d0] = (_Float16)(v0 * rs);
            cp[d1] = (_Float16)(v1 * rs);
        }
    }
}

// ---------------------------------------------------------------- out-proj + LN
// 16 rows/block, grid 128. Wave w -> cols [64w,+64) (4 frags), 1 m-frag.
// Register prefetch of next k-step. Fused residual + LayerNorm -> f16.
__global__ __launch_bounds__(256) void outln_kernel(
    const _Float16* __restrict__ ctx, const float* __restrict__ wo,
    const float* __restrict__ bo, const float* __restrict__ det,
    const float* __restrict__ lng, const float* __restrict__ lnb,
    _Float16* __restrict__ xn)
{
    __shared__ _Float16 As[16][40];
    __shared__ _Float16 Bs[256][40];
    __shared__ float redS[4][16], redQ[4][16], mu[16], rsv[16];

    int tid = threadIdx.x, l = tid & 63, w = tid >> 6;
    int m0 = blockIdx.x * 16, wn = w * 64;
    int ko = (l >> 4) * 8, l15 = l & 15, g = l >> 4;
    int ar = tid >> 2, ac = (tid & 3) * 8;   // As staging (tid < 64)

    f32x4 acc[4]{};

    half8 av{};
    float4 f[8];
    if (tid < 64) av = *(const half8*)(ctx + (long)(m0 + ar) * 256 + ac);
    #pragma unroll
    for (int i = 0; i < 8; ++i)
        f[i] = *(const float4*)(wo + (long)tid * 256 + i * 4);

    for (int k0 = 0; k0 < 256; k0 += 32) {
        __syncthreads();
        if (tid < 64) *(half8*)&As[ar][ac] = av;
        #pragma unroll
        for (int i = 0; i < 4; ++i)
            *(half8*)&Bs[tid][i * 8] = cvt8(f[2 * i], f[2 * i + 1]);
        __syncthreads();
        if (k0 + 32 < 256) {
            if (tid < 64)
                av = *(const half8*)(ctx + (long)(m0 + ar) * 256 + k0 + 32 + ac);
            #pragma unroll
            for (int i = 0; i < 8; ++i)
                f[i] = *(const float4*)(wo + (long)tid * 256 + k0 + 32 + i * 4);
        }
        half8 af = *(const half8*)&As[l15][ko];
        #pragma unroll
        for (int nn = 0; nn < 4; ++nn) {
            half8 bf = *(const half8*)&Bs[wn + nn * 16 + l15][ko];
            acc[nn] = __builtin_amdgcn_mfma_f32_16x16x32_f16(af, bf, acc[nn], 0, 0, 0);
        }
    }

    float bov[4], gv[4], bev[4];
    #pragma unroll
    for (int nn = 0; nn < 4; ++nn) {
        int c = wn + nn * 16 + l15;
        bov[nn] = bo[c]; gv[nn] = lng[c]; bev[nn] = lnb[c];
    }
    #pragma unroll
    for (int i = 0; i < 4; ++i) {
        int r = g * 4 + i;
        float s = 0.f, q = 0.f;
        #pragma unroll
        for (int nn = 0; nn < 4; ++nn) {
            float x = acc[nn][i] + bov[nn]
                    + det[(long)(m0 + r) * 256 + wn + nn * 16 + l15];
            acc[nn][i] = x;
            s += x; q += x * x;
        }
        #pragma unroll
        for (int off = 1; off < 16; off <<= 1) {
            s += __shfl_xor(s, off, 64);
            q += __shfl_xor(q, off, 64);
        }
        if (l15 == 0) { redS[w][r] = s; redQ[w][r] = q; }
    }
    __syncthreads();
    if (tid < 16) {
        float S  = redS[0][tid] + redS[1][tid] + redS[2][tid] + redS[3][tid];
        float Qs = redQ[0][tid] + redQ[1][tid] + redQ[2][tid] + redQ[3][tid];
        float mean = S * (1.f / 256.f);
        float var  = Qs * (1.f / 256.f) - mean * mean;
        mu[tid] = mean;
        rsv[tid] = rsqrtf(var + 1e-5f);
    }
    __syncthreads();
    #pragma unroll
    for (int i = 0; i < 4; ++i) {
        int r = g * 4 + i;
        float mr = mu[r], rr = rsv[r];
        #pragma unroll
        for (int nn = 0; nn < 4; ++nn)
            xn[(long)(m0 + r) * 256 + wn + nn * 16 + l15] =
                (_Float16)((acc[nn][i] - mr) * rr * gv[nn] + bev[nn]);
    }
}

// ---------------------------------------------------------------- pairwise MLP
// Round-6 version verbatim (proven: 83 us, 0 conflicts, WRITE 4.1 MB).
__global__ __launch_bounds__(256) void mlp_kernel(
    const _Float16* __restrict__ xn, const _Float16* __restrict__ trk,
    const _Float16* __restrict__ w1, const float* __restrict__ w2,
    const float* __restrict__ b1, const float* __restrict__ b2,
    float* __restrict__ out)
{
    int b  = blockIdx.z;
    int n0 = blockIdx.x * 32;
    int t0 = blockIdx.y * 32;
    int tid = threadIdx.x;
    int l = tid & 63, w = tid >> 6;
    int l15 = l & 15, g = l >> 4;
    int ko = g * 8;

    __shared__ _Float16 ts[32][264];
    __shared__ float part[4][32][33];

    {
        const _Float16* src = trk + ((long)b * 512 + t0) * 256;
        int r = tid >> 3, c0s = (tid & 7) * 8;
        #pragma unroll
        for (int c = 0; c < 256; c += 64)
            *(half8*)(&ts[r][c + c0s]) = *(const half8*)(src + r * 256 + c + c0s);
    }

    half8 wf[2][8];
    {
        const _Float16* w1p = w1 + (w * 32 + l15) * 256 + ko;
        #pragma unroll
        for (int a = 0; a < 2; ++a)
            #pragma unroll
            for (int ks = 0; ks < 8; ++ks)
                wf[a][ks] = *(const half8*)(w1p + a * 16 * 256 + ks * 32);
    }
    f32x4 binit[2]; f32x4 w2v[2];
    #pragma unroll
    for (int a = 0; a < 2; ++a)
        #pragma unroll
        for (int i = 0; i < 4; ++i) {
            int hh = w * 32 + a * 16 + g * 4 + i;
            binit[a][i] = b1[hh];
            w2v[a][i]   = w2[hh];
        }

    half8 bx[2][8];
    {
        const _Float16* xb = xn + ((long)b * 512 + n0 + l15) * 256 + ko;
        #pragma unroll
        for (int mm = 0; mm < 2; ++mm)
            #pragma unroll
            for (int ks = 0; ks < 8; ++ks)
                bx[mm][ks] = *(const half8*)(xb + mm * 16 * 256 + ks * 32);
    }

    __syncthreads();

    for (int tl = 0; tl < 32; ++tl) {
        f32x4 acc[2][2];
        #pragma unroll
        for (int a = 0; a < 2; ++a) {
            acc[a][0] = binit[a];
            acc[a][1] = binit[a];
        }
        #pragma unroll
        for (int ks = 0; ks < 8; ++ks) {
            half8 tf = *(const half8*)(&ts[tl][ks * 32 + ko]);
            half8 sa0 = wf[0][ks] * tf;
            half8 sa1 = wf[1][ks] * tf;
            acc[0][0] = __builtin_amdgcn_mfma_f32_16x16x32_f16(sa0, bx[0][ks], acc[0][0], 0, 0, 0);
            acc[0][1] = __builtin_amdgcn_mfma_f32_16x16x32_f16(sa0, bx[1][ks], acc[0][1], 0, 0, 0);
            acc[1][0] = __builtin_amdgcn_mfma_f32_16x16x32_f16(sa1, bx[0][ks], acc[1][0], 0, 0, 0);
            acc[1][1] = __builtin_amdgcn_mfma_f32_16x16x32_f16(sa1, bx[1][ks], acc[1][1], 0, 0, 0);
        }
        #pragma unroll
        for (int mm = 0; mm < 2; ++mm) {
            float x = 0.f;
            #pragma unroll
            for (int a = 0; a < 2; ++a)
                #pragma unroll
                for (int i = 0; i < 4; ++i)
                    x = fmaf(fmaxf(acc[a][mm][i], 0.f), w2v[a][i], x);
            x += __shfl_xor(x, 16, 64);
            x += __shfl_xor(x, 32, 64);
            if (g == 0) part[w][tl][mm * 16 + l15] = x;
        }
    }
    __syncthreads();

    float b2v = b2[0];
    int t = tid & 31;
    int nbase = tid >> 5;
    float* op = out + ((long)b * 512 + n0) * 512 + t0;
    #pragma unroll
    for (int k = 0; k < 4; ++k) {
        int nn = nbase + k * 8;
        float s = part[0][t][nn] + part[1][t][nn]
                + part[2][t][nn] + part[3][t][nn] + b2v;
        op[(long)nn * 512 + t] = 1.f / (1.f + __expf(-s));
    }
}

// ---------------------------------------------------------------- launch
extern "C" void kernel_launch(void* const* d_in, const int* in_sizes, int n_in,
                              void* d_out, int out_size, void* d_ws, size_t ws_size,
                              hipStream_t stream)
{
    const float* det  = (const float*)d_in[0];
    const float* trk  = (const float*)d_in[1];
    const float* w_q  = (const float*)d_in[2];
    const float* b_q  = (const float*)d_in[3];
    const float* w_k  = (const float*)d_in[4];
    const float* b_k  = (const float*)d_in[5];
    const float* w_v  = (const float*)d_in[6];
    const float* b_v  = (const float*)d_in[7];
    const float* w_o  = (const float*)d_in[8];
    const float* b_o  = (const float*)d_in[9];
    const float* ln_g = (const float*)d_in[10];
    const float* ln_b = (const float*)d_in[11];
    const float* w1   = (const float*)d_in[12];
    const float* b1   = (const float*)d_in[13];
    const float* w2   = (const float*)d_in[14];
    const float* b2   = (const float*)d_in[15];
    float* out = (float*)d_out;

    char* ws = (char*)d_ws;
    _Float16* Q_h   = (_Float16*)(ws);
    _Float16* K_h   = (_Float16*)(ws + (size_t)1048576);
    _Float16* vt    = (_Float16*)(ws + (size_t)2097152);
    _Float16* ctx_h = (_Float16*)(ws + (size_t)3145728);
    _Float16* xn_h  = (_Float16*)(ws + (size_t)4194304);
    _Float16* trk_h = (_Float16*)(ws + (size_t)5242880);
    _Float16* w1_h  = (_Float16*)(ws + (size_t)6291456);

    // Q/K/V projections + trk/w1 cvt (one launch)
    qkv_kernel<<<dim3(32, 4, 4), 256, 0, stream>>>(
        det, trk, w_q, w_k, w_v, b_q, b_k, b_v, w1, Q_h, K_h, vt, trk_h, w1_h);
    // fused scores + softmax + PV (4-way k-split, 1024 blocks)
    flash_kernel<<<dim3(32, 32), 256, 0, stream>>>(Q_h, K_h, vt, ctx_h);
    // out-proj + residual + LayerNorm -> xn f16 (128 blocks)
    outln_kernel<<<128, 256, 0, stream>>>(ctx_h, w_o, b_o, det, ln_g, ln_b, xn_h);
    // association MLP + sigmoid
    mlp_kernel<<<dim3(16, 16, 4), 256, 0, stream>>>(xn_h, trk_h, w1_h, w2, b1, b2, out);

    (void)in_sizes; (void)n_in; (void)out_size; (void)ws_size;
}

// Round 10
// 187.508 us; speedup vs baseline: 1.1096x; 1.0082x over previous
//
#include <hip/hip_runtime.h>

typedef _Float16 half8 __attribute__((ext_vector_type(8)));
typedef _Float16 half4v __attribute__((ext_vector_type(4)));
typedef _Float16 half2v __attribute__((ext_vector_type(2)));
typedef float f32x4 __attribute__((ext_vector_type(4)));
typedef unsigned u32x2 __attribute__((ext_vector_type(2)));

__device__ __forceinline__ half8 cvt8(const float4 a, const float4 b) {
    half8 r;
    r[0] = (_Float16)a.x; r[1] = (_Float16)a.y; r[2] = (_Float16)a.z; r[3] = (_Float16)a.w;
    r[4] = (_Float16)b.x; r[5] = (_Float16)b.y; r[6] = (_Float16)b.z; r[7] = (_Float16)b.w;
    return r;
}

// sum over the 4 lanes {l, l^16, l^32, l^48}; result valid in ALL lanes.
// xor16 via documented ds_swizzle BitMode (0x401F); xor32 via permlane32_swap
// summing BOTH outputs (r0+r1 = x[l]+x[l^32] under either swap convention).
__device__ __forceinline__ float grp_sum4(float x) {
    x += __int_as_float(__builtin_amdgcn_ds_swizzle(__float_as_int(x), 0x401F));
    u32x2 r = __builtin_amdgcn_permlane32_swap(__float_as_uint(x), __float_as_uint(x),
                                               false, false);
    return __uint_as_float(r[0]) + __uint_as_float(r[1]);
}

// ---------------------------------------------------------------- QKV + cvt
// z in {0:Q, 1:K, 2:V-scatter, 3: trk/w1 f32->f16 cvt for mlp}.
// GEMM core = proven 64x64 gemm_tn with register prefetch of next k-step.
__global__ __launch_bounds__(256) void qkv_kernel(
    const float* __restrict__ det, const float* __restrict__ trk,
    const float* __restrict__ wq, const float* __restrict__ wk,
    const float* __restrict__ wv, const float* __restrict__ bq,
    const float* __restrict__ bk, const float* __restrict__ bv,
    const float* __restrict__ w1,
    _Float16* __restrict__ Qh, _Float16* __restrict__ Kh,
    _Float16* __restrict__ vt, _Float16* __restrict__ trk_h,
    _Float16* __restrict__ w1_h)
{
    int z = blockIdx.z;
    if (z == 3) {   // elementwise cvt: trk (131072 float4) + w1 (8192 float4)
        int flat = blockIdx.y * 32 + blockIdx.x;          // 0..127
        int t0 = flat * 256 + threadIdx.x;                // stride 32768
        for (int i = t0; i < 131072; i += 32768) {
            float4 v = ((const float4*)trk)[i];
            half4v h; h[0]=(_Float16)v.x; h[1]=(_Float16)v.y; h[2]=(_Float16)v.z; h[3]=(_Float16)v.w;
            *(half4v*)(trk_h + (long)i * 4) = h;
        }
        if (t0 < 8192) {
            float4 v = ((const float4*)w1)[t0];
            half4v h; h[0]=(_Float16)v.x; h[1]=(_Float16)v.y; h[2]=(_Float16)v.z; h[3]=(_Float16)v.w;
            *(half4v*)(w1_h + (long)t0 * 4) = h;
        }
        return;
    }
    const float* A    = (z == 0) ? det : trk;
    const float* Bm   = (z == 0) ? wq : (z == 1) ? wk : wv;
    const float* bias = (z == 0) ? bq : (z == 1) ? bk : bv;

    __shared__ _Float16 As[64][40];
    __shared__ _Float16 Bs[64][40];

    int tid = threadIdx.x, l = tid & 63, w = tid >> 6;
    int wm = (w >> 1) * 32, wn = (w & 1) * 32;
    int m0 = blockIdx.x * 64, n0 = blockIdx.y * 64;
    int lr = tid >> 2, lc = (tid & 3) * 8;
    int ko = (l >> 4) * 8, l15 = l & 15;

    f32x4 acc[2][2]{};

    // prefetch k0 = 0
    float4 a0 = *(const float4*)(A + (long)(m0 + lr) * 256 + lc);
    float4 a1 = *(const float4*)(A + (long)(m0 + lr) * 256 + lc + 4);
    float4 b0 = *(const float4*)(Bm + (long)(n0 + lr) * 256 + lc);
    float4 b1 = *(const float4*)(Bm + (long)(n0 + lr) * 256 + lc + 4);

    for (int k0 = 0; k0 < 256; k0 += 32) {
        __syncthreads();
        *(half8*)&As[lr][lc] = cvt8(a0, a1);
        *(half8*)&Bs[lr][lc] = cvt8(b0, b1);
        __syncthreads();
        if (k0 + 32 < 256) {   // issue next-step loads; overlap MFMA + barrier
            a0 = *(const float4*)(A + (long)(m0 + lr) * 256 + k0 + 32 + lc);
            a1 = *(const float4*)(A + (long)(m0 + lr) * 256 + k0 + 32 + lc + 4);
            b0 = *(const float4*)(Bm + (long)(n0 + lr) * 256 + k0 + 32 + lc);
            b1 = *(const float4*)(Bm + (long)(n0 + lr) * 256 + k0 + 32 + lc + 4);
        }
        half8 af0 = *(const half8*)(&As[wm + l15][ko]);
        half8 af1 = *(const half8*)(&As[wm + 16 + l15][ko]);
        half8 bf0 = *(const half8*)(&Bs[wn + l15][ko]);
        half8 bf1 = *(const half8*)(&Bs[wn + 16 + l15][ko]);
        acc[0][0] = __builtin_amdgcn_mfma_f32_16x16x32_f16(af0, bf0, acc[0][0], 0, 0, 0);
        acc[0][1] = __builtin_amdgcn_mfma_f32_16x16x32_f16(af0, bf1, acc[0][1], 0, 0, 0);
        acc[1][0] = __builtin_amdgcn_mfma_f32_16x16x32_f16(af1, bf0, acc[1][0], 0, 0, 0);
        acc[1][1] = __builtin_amdgcn_mfma_f32_16x16x32_f16(af1, bf1, acc[1][1], 0, 0, 0);
    }

    #pragma unroll
    for (int mm = 0; mm < 2; ++mm)
    #pragma unroll
    for (int nn = 0; nn < 2; ++nn) {
        int row  = wm + mm * 16 + (l >> 4) * 4;
        int colg = n0 + wn + nn * 16 + l15;
        float bc = bias[colg];
        if (z == 2) {
            half4v hv;
            #pragma unroll
            for (int i = 0; i < 4; ++i) hv[i] = (_Float16)(acc[mm][nn][i] + bc);
            int grow = m0 + row;
            int bb = grow >> 9, t = grow & 511;
            long off = ((long)(bb * 8 + (colg >> 5)) * 32 + (colg & 31)) * 512 + t;
            *(half4v*)(vt + off) = hv;
        } else {
            _Float16* C = (z == 0) ? Qh : Kh;
            #pragma unroll
            for (int i = 0; i < 4; ++i)
                C[(long)(m0 + row + i) * 256 + colg] = (_Float16)(acc[mm][nn][i] + bc);
        }
    }
}

// ---------------------------------------------------------------- fused attention
// 4-way k-split (round-9, passed): block = 16 q x (b,h); wave w owns k-quarter.
__global__ __launch_bounds__(256) void flash_kernel(
    const _Float16* __restrict__ Q, const _Float16* __restrict__ K,
    const _Float16* __restrict__ vt, _Float16* __restrict__ ctx)
{
    __shared__ _Float16 P[4][16][136];
    __shared__ float cbuf[4][16][33];
    __shared__ float mbuf[4][16], sbuf[4][16];

    int bh = blockIdx.y, b = bh >> 3, h = bh & 7;
    int q0 = blockIdx.x * 16;
    int tid = threadIdx.x, l = tid & 63, w = tid >> 6;
    int l15 = l & 15, g = l >> 4;

    const _Float16* qp = Q + ((long)b * 512 + q0 + l15) * 256 + h * 32 + g * 8;
    half8 qf = *(const half8*)qp;
    #pragma unroll
    for (int i = 0; i < 8; ++i) qf[i] = qf[i] * (_Float16)0.17677669529663687f;

    const _Float16* kp = K + ((long)b * 512 + w * 128 + l15) * 256 + h * 32 + g * 8;
    const _Float16* vp = vt + ((long)bh * 32 + l15) * 512 + w * 128 + g * 8;

    f32x4 zero{};
    f32x4 s[8];
    #pragma unroll
    for (int t = 0; t < 8; ++t) {
        half8 kf = *(const half8*)(kp + (long)t * (16 * 256));
        s[t] = __builtin_amdgcn_mfma_f32_16x16x32_f16(kf, qf, zero, 0, 0, 0);
    }
    float m0 = -3e38f, m1 = -3e38f, m2 = -3e38f, m3 = -3e38f;
    #pragma unroll
    for (int t = 0; t < 8; ++t) {
        m0 = fmaxf(m0, s[t][0]); m1 = fmaxf(m1, s[t][1]);
        m2 = fmaxf(m2, s[t][2]); m3 = fmaxf(m3, s[t][3]);
    }
    float m_loc = fmaxf(fmaxf(m0, m1), fmaxf(m2, m3));
    m_loc = fmaxf(m_loc, __shfl_xor(m_loc, 16, 64));
    m_loc = fmaxf(m_loc, __shfl_xor(m_loc, 32, 64));
    float s0 = 0.f, s1 = 0.f, s2 = 0.f, s3 = 0.f;
    #pragma unroll
    for (int t = 0; t < 8; ++t) {
        s[t][0] = __expf(s[t][0] - m_loc); s0 += s[t][0];
        s[t][1] = __expf(s[t][1] - m_loc); s1 += s[t][1];
        s[t][2] = __expf(s[t][2] - m_loc); s2 += s[t][2];
        s[t][3] = __expf(s[t][3] - m_loc); s3 += s[t][3];
    }
    float sum_loc = (s0 + s1) + (s2 + s3);
    sum_loc += __shfl_xor(sum_loc, 16, 64);
    sum_loc += __shfl_xor(sum_loc, 32, 64);

    #pragma unroll
    for (int t = 0; t < 8; ++t) {
        half2v p01, p23;
        p01[0] = (_Float16)s[t][0]; p01[1] = (_Float16)s[t][1];
        p23[0] = (_Float16)s[t][2]; p23[1] = (_Float16)s[t][3];
        *(half2v*)&P[w][l15][t * 16 + g * 4]     = p01;
        *(half2v*)&P[w][l15][t * 16 + g * 4 + 2] = p23;
    }
    f32x4 c0{}, c1{};
    #pragma unroll
    for (int s2i = 0; s2i < 4; ++s2i) {
        half8 bf = *(const half8*)&P[w][l15][s2i * 32 + g * 8];
        half8 a0 = *(const half8*)(vp + s2i * 32);
        half8 a1 = *(const half8*)(vp + 16 * 512 + s2i * 32);
        c0 = __builtin_amdgcn_mfma_f32_16x16x32_f16(a0, bf, c0, 0, 0, 0);
        c1 = __builtin_amdgcn_mfma_f32_16x16x32_f16(a1, bf, c1, 0, 0, 0);
    }
    if (g == 0) { mbuf[w][l15] = m_loc; sbuf[w][l15] = sum_loc; }
    #pragma unroll
    for (int i = 0; i < 4; ++i) {
        cbuf[w][l15][g * 4 + i]      = c0[i];
        cbuf[w][l15][16 + g * 4 + i] = c1[i];
    }
    __syncthreads();
    if (w == 0) {
        float ma = fmaxf(fmaxf(mbuf[0][l15], mbuf[1][l15]),
                         fmaxf(mbuf[2][l15], mbuf[3][l15]));
        float e0 = __expf(mbuf[0][l15] - ma), e1 = __expf(mbuf[1][l15] - ma);
        float e2 = __expf(mbuf[2][l15] - ma), e3 = __expf(mbuf[3][l15] - ma);
        float den = sbuf[0][l15] * e0 + sbuf[1][l15] * e1
                  + sbuf[2][l15] * e2 + sbuf[3][l15] * e3;
        float rs = 1.f / den;
        _Float16* cp = ctx + ((long)b * 512 + q0 + l15) * 256 + h * 32;
        #pragma unroll
        for (int i = 0; i < 4; ++i) {
            int d0 = g * 4 + i, d1 = 16 + g * 4 + i;
            float v0 = cbuf[0][l15][d0] * e0 + cbuf[1][l15][d0] * e1
                     + cbuf[2][l15][d0] * e2 + cbuf[3][l15][d0] * e3;
            float v1 = cbuf[0][l15][d1] * e0 + cbuf[1][l15][d1] * e1
                     + cbuf[2][l15][d1] * e2 + cbuf[3][l15][d1] * e3;
            cp[d0] = (_Float16)(v0 * rs);
            cp[d1] = (_Float16)(v1 * rs);
        }
    }
}

// ---------------------------------------------------------------- out-proj + LN
// 16 rows/block, grid 128 (round-9, passed).
__global__ __launch_bounds__(256) void outln_kernel(
    const _Float16* __restrict__ ctx, const float* __restrict__ wo,
    const float* __restrict__ bo, const float* __restrict__ det,
    const float* __restrict__ lng, const float* __restrict__ lnb,
    _Float16* __restrict__ xn)
{
    __shared__ _Float16 As[16][40];
    __shared__ _Float16 Bs[256][40];
    __shared__ float redS[4][16], redQ[4][16], mu[16], rsv[16];

    int tid = threadIdx.x, l = tid & 63, w = tid >> 6;
    int m0 = blockIdx.x * 16, wn = w * 64;
    int ko = (l >> 4) * 8, l15 = l & 15, g = l >> 4;
    int ar = tid >> 2, ac = (tid & 3) * 8;

    f32x4 acc[4]{};

    half8 av{};
    float4 f[8];
    if (tid < 64) av = *(const half8*)(ctx + (long)(m0 + ar) * 256 + ac);
    #pragma unroll
    for (int i = 0; i < 8; ++i)
        f[i] = *(const float4*)(wo + (long)tid * 256 + i * 4);

    for (int k0 = 0; k0 < 256; k0 += 32) {
        __syncthreads();
        if (tid < 64) *(half8*)&As[ar][ac] = av;
        #pragma unroll
        for (int i = 0; i < 4; ++i)
            *(half8*)&Bs[tid][i * 8] = cvt8(f[2 * i], f[2 * i + 1]);
        __syncthreads();
        if (k0 + 32 < 256) {
            if (tid < 64)
                av = *(const half8*)(ctx + (long)(m0 + ar) * 256 + k0 + 32 + ac);
            #pragma unroll
            for (int i = 0; i < 8; ++i)
                f[i] = *(const float4*)(wo + (long)tid * 256 + k0 + 32 + i * 4);
        }
        half8 af = *(const half8*)&As[l15][ko];
        #pragma unroll
        for (int nn = 0; nn < 4; ++nn) {
            half8 bf = *(const half8*)&Bs[wn + nn * 16 + l15][ko];
            acc[nn] = __builtin_amdgcn_mfma_f32_16x16x32_f16(af, bf, acc[nn], 0, 0, 0);
        }
    }

    float bov[4], gv[4], bev[4];
    #pragma unroll
    for (int nn = 0; nn < 4; ++nn) {
        int c = wn + nn * 16 + l15;
        bov[nn] = bo[c]; gv[nn] = lng[c]; bev[nn] = lnb[c];
    }
    #pragma unroll
    for (int i = 0; i < 4; ++i) {
        int r = g * 4 + i;
        float s = 0.f, q = 0.f;
        #pragma unroll
        for (int nn = 0; nn < 4; ++nn) {
            float x = acc[nn][i] + bov[nn]
                    + det[(long)(m0 + r) * 256 + wn + nn * 16 + l15];
            acc[nn][i] = x;
            s += x; q += x * x;
        }
        #pragma unroll
        for (int off = 1; off < 16; off <<= 1) {
            s += __shfl_xor(s, off, 64);
            q += __shfl_xor(q, off, 64);
        }
        if (l15 == 0) { redS[w][r] = s; redQ[w][r] = q; }
    }
    __syncthreads();
    if (tid < 16) {
        float S  = redS[0][tid] + redS[1][tid] + redS[2][tid] + redS[3][tid];
        float Qs = redQ[0][tid] + redQ[1][tid] + redQ[2][tid] + redQ[3][tid];
        float mean = S * (1.f / 256.f);
        float var  = Qs * (1.f / 256.f) - mean * mean;
        mu[tid] = mean;
        rsv[tid] = rsqrtf(var + 1e-5f);
    }
    __syncthreads();
    #pragma unroll
    for (int i = 0; i < 4; ++i) {
        int r = g * 4 + i;
        float mr = mu[r], rr = rsv[r];
        #pragma unroll
        for (int nn = 0; nn < 4; ++nn)
            xn[(long)(m0 + r) * 256 + wn + nn * 16 + l15] =
                (_Float16)((acc[nn][i] - mr) * rr * gv[nn] + bev[nn]);
    }
}

// ---------------------------------------------------------------- pairwise MLP
// Round-6 skeleton + fixes:
//  - __launch_bounds__(256,1): VGPR_Count=100 < wf+bx=128 demand proved the
//    compiler was reloading fragments from L2 inside the t-loop (VALU 3.5x
//    hand-count). Lift the cap so wf/bx/acc stay register-resident.
//  - grp_sum4 (ds_swizzle xor16 + permlane32_swap) replaces shfl chains.
//  - part buffer in f16 (logit quarters O(5); adds <=1e-3 sigmoid error).
__global__ __launch_bounds__(256, 1) void mlp_kernel(
    const _Float16* __restrict__ xn, const _Float16* __restrict__ trk,
    const _Float16* __restrict__ w1, const float* __restrict__ w2,
    const float* __restrict__ b1, const float* __restrict__ b2,
    float* __restrict__ out)
{
    int b  = blockIdx.z;
    int n0 = blockIdx.x * 32;
    int t0 = blockIdx.y * 32;
    int tid = threadIdx.x;
    int l = tid & 63, w = tid >> 6;
    int l15 = l & 15, g = l >> 4;
    int ko = g * 8;

    __shared__ _Float16 ts[32][264];
    __shared__ _Float16 part[4][32][34];

    {
        const _Float16* src = trk + ((long)b * 512 + t0) * 256;
        int r = tid >> 3, c0s = (tid & 7) * 8;
        #pragma unroll
        for (int c = 0; c < 256; c += 64)
            *(half8*)(&ts[r][c + c0s]) = *(const half8*)(src + r * 256 + c + c0s);
    }

    half8 wf[2][8];
    {
        const _Float16* w1p = w1 + (w * 32 + l15) * 256 + ko;
        #pragma unroll
        for (int a = 0; a < 2; ++a)
            #pragma unroll
            for (int ks = 0; ks < 8; ++ks)
                wf[a][ks] = *(const half8*)(w1p + a * 16 * 256 + ks * 32);
    }
    f32x4 binit[2]; f32x4 w2v[2];
    #pragma unroll
    for (int a = 0; a < 2; ++a)
        #pragma unroll
        for (int i = 0; i < 4; ++i) {
            int hh = w * 32 + a * 16 + g * 4 + i;
            binit[a][i] = b1[hh];
            w2v[a][i]   = w2[hh];
        }

    half8 bx[2][8];
    {
        const _Float16* xb = xn + ((long)b * 512 + n0 + l15) * 256 + ko;
        #pragma unroll
        for (int mm = 0; mm < 2; ++mm)
            #pragma unroll
            for (int ks = 0; ks < 8; ++ks)
                bx[mm][ks] = *(const half8*)(xb + mm * 16 * 256 + ks * 32);
    }

    __syncthreads();

    for (int tl = 0; tl < 32; ++tl) {
        f32x4 acc[2][2];
        #pragma unroll
        for (int a = 0; a < 2; ++a) {
            acc[a][0] = binit[a];
            acc[a][1] = binit[a];
        }
        #pragma unroll
        for (int ks = 0; ks < 8; ++ks) {
            half8 tf = *(const half8*)(&ts[tl][ks * 32 + ko]);
            half8 sa0 = wf[0][ks] * tf;
            half8 sa1 = wf[1][ks] * tf;
            acc[0][0] = __builtin_amdgcn_mfma_f32_16x16x32_f16(sa0, bx[0][ks], acc[0][0], 0, 0, 0);
            acc[0][1] = __builtin_amdgcn_mfma_f32_16x16x32_f16(sa0, bx[1][ks], acc[0][1], 0, 0, 0);
            acc[1][0] = __builtin_amdgcn_mfma_f32_16x16x32_f16(sa1, bx[0][ks], acc[1][0], 0, 0, 0);
            acc[1][1] = __builtin_amdgcn_mfma_f32_16x16x32_f16(sa1, bx[1][ks], acc[1][1], 0, 0, 0);
        }
        #pragma unroll
        for (int mm = 0; mm < 2; ++mm) {
            float x = 0.f;
            #pragma unroll
            for (int a = 0; a < 2; ++a)
                #pragma unroll
                for (int i = 0; i < 4; ++i)
                    x = fmaf(fmaxf(acc[a][mm][i], 0.f), w2v[a][i], x);
            x = grp_sum4(x);
            if (g == 0) part[w][tl][mm * 16 + l15] = (_Float16)x;
        }
    }
    __syncthreads();

    float b2v = b2[0];
    int t = tid & 31;
    int nbase = tid >> 5;
    float* op = out + ((long)b * 512 + n0) * 512 + t0;
    #pragma unroll
    for (int k = 0; k < 4; ++k) {
        int nn = nbase + k * 8;
        float s = (float)part[0][t][nn] + (float)part[1][t][nn]
                + (float)part[2][t][nn] + (float)part[3][t][nn] + b2v;
        op[(long)nn * 512 + t] = 1.f / (1.f + __expf(-s));
    }
}

// ---------------------------------------------------------------- launch
extern "C" void kernel_launch(void* const* d_in, const int* in_sizes, int n_in,
                              void* d_out, int out_size, void* d_ws, size_t ws_size,
                              hipStream_t stream)
{
    const float* det  = (const float*)d_in[0];
    const float* trk  = (const float*)d_in[1];
    const float* w_q  = (const float*)d_in[2];
    const float* b_q  = (const float*)d_in[3];
    const float* w_k  = (const float*)d_in[4];
    const float* b_k  = (const float*)d_in[5];
    const float* w_v  = (const float*)d_in[6];
    const float* b_v  = (const float*)d_in[7];
    const float* w_o  = (const float*)d_in[8];
    const float* b_o  = (const float*)d_in[9];
    const float* ln_g = (const float*)d_in[10];
    const float* ln_b = (const float*)d_in[11];
    const float* w1   = (const float*)d_in[12];
    const float* b1   = (const float*)d_in[13];
    const float* w2   = (const float*)d_in[14];
    const float* b2   = (const float*)d_in[15];
    float* out = (float*)d_out;

    char* ws = (char*)d_ws;
    _Float16* Q_h   = (_Float16*)(ws);
    _Float16* K_h   = (_Float16*)(ws + (size_t)1048576);
    _Float16* vt    = (_Float16*)(ws + (size_t)2097152);
    _Float16* ctx_h = (_Float16*)(ws + (size_t)3145728);
    _Float16* xn_h  = (_Float16*)(ws + (size_t)4194304);
    _Float16* trk_h = (_Float16*)(ws + (size_t)5242880);
    _Float16* w1_h  = (_Float16*)(ws + (size_t)6291456);

    // Q/K/V projections + trk/w1 cvt (one launch)
    qkv_kernel<<<dim3(32, 4, 4), 256, 0, stream>>>(
        det, trk, w_q, w_k, w_v, b_q, b_k, b_v, w1, Q_h, K_h, vt, trk_h, w1_h);
    // fused scores + softmax + PV (4-way k-split, 1024 blocks)
    flash_kernel<<<dim3(32, 32), 256, 0, stream>>>(Q_h, K_h, vt, ctx_h);
    // out-proj + residual + LayerNorm -> xn f16 (128 blocks)
    outln_kernel<<<128, 256, 0, stream>>>(ctx_h, w_o, b_o, det, ln_g, ln_b, xn_h);
    // association MLP + sigmoid
    mlp_kernel<<<dim3(16, 16, 4), 256, 0, stream>>>(xn_h, trk_h, w1_h, w2, b1, b2, out);

    (void)in_sizes; (void)n_in; (void)out_size; (void)ws_size;
}